// Round 5
// baseline (619.524 us; speedup 1.0000x reference)
//
#include <hip/hip_runtime.h>
#include <stdint.h>

#define D 512

typedef _Float16 f16;
typedef f16 f16x8 __attribute__((ext_vector_type(8)));
typedef f16 h2 __attribute__((ext_vector_type(2)));
typedef float f32x4 __attribute__((ext_vector_type(4)));
typedef unsigned int u32;
typedef u32 u32x4 __attribute__((ext_vector_type(4)));

static __device__ __forceinline__ u32 bcu(h2 h) { return __builtin_bit_cast(u32, h); }
static __device__ __forceinline__ h2 pkrtz(float a, float b) {
  return __builtin_bit_cast(h2, __builtin_amdgcn_cvt_pkrtz(a, b));
}
static __device__ __forceinline__ f16x8 frag4(u32 w0, u32 w1, u32 w2, u32 w3) {
  u32x4 u = {w0, w1, w2, w3};
  return __builtin_bit_cast(f16x8, u);
}
static __device__ __forceinline__ float fastrcp(float x) {
#if __has_builtin(__builtin_amdgcn_rcpf)
  return __builtin_amdgcn_rcpf(x);
#else
  return 1.0f / x;
#endif
}

// lhi-repack: C-layout tile pair (lane l15 = col, regs m = 4*lhi+r, plus m=16 value
// valid only on lhi==0 lanes, 0 elsewhere) -> A/B-frag (same l15, k=m=lhi*8+j, m17..31=0).
static __device__ __forceinline__ f16x8 repack_frag(float c0, float c1, float c2, float c3,
                                                    float v16, int l15, int lhi) {
  u32 t0a = bcu(pkrtz(c0, c1)), t0b = bcu(pkrtz(c2, c3));
  u32 t1a = bcu(pkrtz(v16, 0.f));
  int srcA = (((lhi * 2) & 3) << 4) | l15;
  int srcB = (((lhi * 2 + 1) & 3) << 4) | l15;
  u32 a0 = (u32)__shfl((int)t0a, srcA);
  u32 a1 = (u32)__shfl((int)t0b, srcA);
  u32 a2 = (u32)__shfl((int)t1a, srcA);
  u32 b0 = (u32)__shfl((int)t0a, srcB);
  u32 b1 = (u32)__shfl((int)t0b, srcB);
  u32 b2 = (u32)__shfl((int)t1a, srcB);
  bool lo = lhi < 2;
  return frag4(lo ? a0 : a2, lo ? a1 : 0u, lo ? b0 : b2, lo ? b1 : 0u);
}

// ---------------- prep: Wcat f16 [h][k|v][d][i] + bcat + Wqh f16 [o][i] ----------------
__global__ __launch_bounds__(256) void prep_k(
    const float* __restrict__ Wq, const float* __restrict__ Wk,
    const float* __restrict__ bk, const float* __restrict__ Wv,
    const float* __restrict__ bv, f16* __restrict__ Wcat,
    float* __restrict__ bcat, f16* __restrict__ Wqh) {
  int bid = blockIdx.x, tid = threadIdx.x;
  if (bid < 1024) {
    int h = bid >> 7, kvs = (bid >> 6) & 1, d = bid & 63;
    int srow = h * 64 + d;
    const float* src = (kvs ? Wv : Wk) + (size_t)srow * D;
    f16* dst = Wcat + (size_t)bid * D;
    for (int i = tid; i < D; i += 256) dst[i] = (f16)src[i];
    if (tid == 0) bcat[bid] = (kvs ? bv : bk)[srow];
  } else {
    int o = bid - 1024;
    for (int i = tid; i < D; i += 256) Wqh[(size_t)o * D + i] = (f16)Wq[(size_t)o * D + i];
  }
}

// ---------------- qproj (MFMA): q16h[h][bs][n][64] = LN(xf) @ Wq^T + bq ----------------
// grid (16 bs, 5 mtile); 4 waves; LDS xn 16 rows x 1024B swizzled.
__global__ __launch_bounds__(256) void qproj_k(
    const float* __restrict__ xf, const float* __restrict__ tn_g,
    const float* __restrict__ tn_b, const f16* __restrict__ Wqh,
    const float* __restrict__ bq, f16* __restrict__ q16h) {
  __shared__ __align__(16) unsigned char lds[16384];
  const int bs = blockIdx.x, n0 = blockIdx.y * 16;
  const int tid = threadIdx.x, wv = tid >> 6, lane = tid & 63;
  const int l15 = lane & 15, lhi = lane >> 4;

  for (int rr = wv; rr < 16; rr += 4) {
    int srcn = n0 + rr;
    if (srcn > 76) srcn = 76;
    const f32x4* xr = (const f32x4*)(xf + ((size_t)(bs * 77 + srcn)) * D);
    f32x4 va = xr[lane * 2], vb = xr[lane * 2 + 1];
    float s = va[0] + va[1] + va[2] + va[3] + vb[0] + vb[1] + vb[2] + vb[3];
    float sq = va[0] * va[0] + va[1] * va[1] + va[2] * va[2] + va[3] * va[3] +
               vb[0] * vb[0] + vb[1] * vb[1] + vb[2] * vb[2] + vb[3] * vb[3];
#pragma unroll
    for (int off = 32; off; off >>= 1) {
      s += __shfl_xor(s, off);
      sq += __shfl_xor(sq, off);
    }
    float mu = s * (1.0f / 512.0f);
    float var = sq * (1.0f / 512.0f) - mu * mu;
    float rstd = rsqrtf(var + 1e-5f);
    f32x4 ga = ((const f32x4*)tn_g)[lane * 2], gb = ((const f32x4*)tn_g)[lane * 2 + 1];
    f32x4 ba = ((const f32x4*)tn_b)[lane * 2], bb = ((const f32x4*)tn_b)[lane * 2 + 1];
    uint4 u;
    u.x = bcu(pkrtz((va[0] - mu) * rstd * ga[0] + ba[0], (va[1] - mu) * rstd * ga[1] + ba[1]));
    u.y = bcu(pkrtz((va[2] - mu) * rstd * ga[2] + ba[2], (va[3] - mu) * rstd * ga[3] + ba[3]));
    u.z = bcu(pkrtz((vb[0] - mu) * rstd * gb[0] + bb[0], (vb[1] - mu) * rstd * gb[1] + bb[1]));
    u.w = bcu(pkrtz((vb[2] - mu) * rstd * gb[2] + bb[2], (vb[3] - mu) * rstd * gb[3] + bb[3]));
    *reinterpret_cast<uint4*>(lds + rr * 1024 + ((lane * 16) ^ ((rr & 7) << 4))) = u;
  }
  __syncthreads();

  f32x4 acc[8];
#pragma unroll
  for (int nt = 0; nt < 8; ++nt) {
    float bias = bq[wv * 128 + nt * 16 + l15];
    acc[nt] = (f32x4){bias, bias, bias, bias};
  }
  for (int ks = 0; ks < 16; ++ks) {
    f16x8 af = *(const f16x8*)(lds + l15 * 1024 + ((ks * 64 + lhi * 16) ^ ((l15 & 7) << 4)));
#pragma unroll
    for (int nt = 0; nt < 8; ++nt) {
      f16x8 bf = *(const f16x8*)(Wqh + (size_t)(wv * 128 + nt * 16 + l15) * D + ks * 32 + lhi * 8);
      acc[nt] = __builtin_amdgcn_mfma_f32_16x16x32_f16(af, bf, acc[nt], 0, 0, 0);
    }
  }
#pragma unroll
  for (int nt = 0; nt < 8; ++nt) {
    int col = wv * 128 + nt * 16 + l15;
    int h = col >> 6, d = col & 63;
    f16* base = q16h + ((size_t)(h * 16 + bs) * 77) * 64;
#pragma unroll
    for (int r = 0; r < 4; ++r) {
      int n = n0 + lhi * 4 + r;
      if (n < 77) base[n * 64 + d] = (f16)acc[nt][r];
    }
  }
}

// ---------------- fused: LN -> wave-private K,V proj -> S^T attention -> out ----------------
// 1 batch per block (grid 3888), 4 waves, each wave owns 2 heads end-to-end.
// LDS: xn [17][1024B swz] = 17408 + per-wave K scratch [17 m][144B] (2560 aligned) x4.
// Exactly ONE barrier per block.
#define KS_BASE 17408
#define LDS_TOTAL (17408 + 4 * 2560)

__global__ __launch_bounds__(256, 4) void fused_k(
    const float* __restrict__ x, const float* __restrict__ n_g,
    const float* __restrict__ n_b, const f16* __restrict__ Wcat,
    const float* __restrict__ bcat, const f16* __restrict__ q16h,
    float* __restrict__ out) {
  __shared__ __align__(16) unsigned char lds[LDS_TOTAL];
  const int b = blockIdx.x, bs = b & 15;
  const int tid = threadIdx.x, wv = tid >> 6, lane = tid & 63;
  const int l15 = lane & 15, lhi = lane >> 4;

  // Phase 1: LayerNorm -> xn f16 rows 0..16 (swizzled)
  for (int rr = wv; rr < 17; rr += 4) {
    const f32x4* xr = (const f32x4*)(x + ((size_t)(b * 17 + rr)) * D);
    f32x4 va = xr[lane * 2], vb = xr[lane * 2 + 1];
    float s = va[0] + va[1] + va[2] + va[3] + vb[0] + vb[1] + vb[2] + vb[3];
    float sq = va[0] * va[0] + va[1] * va[1] + va[2] * va[2] + va[3] * va[3] +
               vb[0] * vb[0] + vb[1] * vb[1] + vb[2] * vb[2] + vb[3] * vb[3];
#pragma unroll
    for (int off = 32; off; off >>= 1) {
      s += __shfl_xor(s, off);
      sq += __shfl_xor(sq, off);
    }
    float mu = s * (1.0f / 512.0f);
    float var = sq * (1.0f / 512.0f) - mu * mu;
    float rstd = rsqrtf(var + 1e-5f);
    f32x4 ga = ((const f32x4*)n_g)[lane * 2], gb = ((const f32x4*)n_g)[lane * 2 + 1];
    f32x4 ba = ((const f32x4*)n_b)[lane * 2], bb = ((const f32x4*)n_b)[lane * 2 + 1];
    uint4 u;
    u.x = bcu(pkrtz((va[0] - mu) * rstd * ga[0] + ba[0], (va[1] - mu) * rstd * ga[1] + ba[1]));
    u.y = bcu(pkrtz((va[2] - mu) * rstd * ga[2] + ba[2], (va[3] - mu) * rstd * ga[3] + ba[3]));
    u.z = bcu(pkrtz((vb[0] - mu) * rstd * gb[0] + bb[0], (vb[1] - mu) * rstd * gb[1] + bb[1]));
    u.w = bcu(pkrtz((vb[2] - mu) * rstd * gb[2] + bb[2], (vb[3] - mu) * rstd * gb[3] + bb[3]));
    *reinterpret_cast<uint4*>(lds + rr * 1024 + ((lane * 16) ^ ((rr & 7) << 4))) = u;
  }
  __syncthreads();

  unsigned char* ksb = lds + KS_BASE + wv * 2560;

  for (int hp = 0; hp < 2; ++hp) {
    const int head = hp * 4 + wv;
    const f16* wkb = Wcat + (size_t)(head * 128) * D;

    // ---- K projection (M rows = t 0..16; tile1 clamped to row 16) ----
    f32x4 accK[2][4];
#pragma unroll
    for (int nt = 0; nt < 4; ++nt) {
      float bias = bcat[head * 128 + nt * 16 + l15];
      accK[0][nt] = (f32x4){bias, bias, bias, bias};
      accK[1][nt] = accK[0][nt];
    }
    for (int ks = 0; ks < 16; ++ks) {
      f16x8 af0 = *(const f16x8*)(lds + l15 * 1024 + ((ks * 64 + lhi * 16) ^ ((l15 & 7) << 4)));
      f16x8 af1 = *(const f16x8*)(lds + 16 * 1024 + ks * 64 + lhi * 16);
#pragma unroll
      for (int nt = 0; nt < 4; ++nt) {
        f16x8 bf = *(const f16x8*)(wkb + (size_t)(nt * 16 + l15) * D + ks * 32 + lhi * 8);
        accK[0][nt] = __builtin_amdgcn_mfma_f32_16x16x32_f16(af0, bf, accK[0][nt], 0, 0, 0);
        accK[1][nt] = __builtin_amdgcn_mfma_f32_16x16x32_f16(af1, bf, accK[1][nt], 0, 0, 0);
      }
    }
    // store K to wave-private LDS as [m][d] (stride 144B)
#pragma unroll
    for (int nt = 0; nt < 4; ++nt) {
#pragma unroll
      for (int r = 0; r < 4; ++r)
        *(f16*)(ksb + (lhi * 4 + r) * 144 + (nt * 16 + l15) * 2) = (f16)accK[0][nt][r];
      if (lhi == 0) *(f16*)(ksb + 16 * 144 + (nt * 16 + l15) * 2) = (f16)accK[1][nt][0];
    }

    // ---- V projection ----
    const f16* wvb = wkb + (size_t)64 * D;
    f32x4 accV[2][4];
#pragma unroll
    for (int nt = 0; nt < 4; ++nt) {
      float bias = bcat[head * 128 + 64 + nt * 16 + l15];
      accV[0][nt] = (f32x4){bias, bias, bias, bias};
      accV[1][nt] = accV[0][nt];
    }
    for (int ks = 0; ks < 16; ++ks) {
      f16x8 af0 = *(const f16x8*)(lds + l15 * 1024 + ((ks * 64 + lhi * 16) ^ ((l15 & 7) << 4)));
      f16x8 af1 = *(const f16x8*)(lds + 16 * 1024 + ks * 64 + lhi * 16);
#pragma unroll
      for (int nt = 0; nt < 4; ++nt) {
        f16x8 bf = *(const f16x8*)(wvb + (size_t)(nt * 16 + l15) * D + ks * 32 + lhi * 8);
        accV[0][nt] = __builtin_amdgcn_mfma_f32_16x16x32_f16(af0, bf, accV[0][nt], 0, 0, 0);
        accV[1][nt] = __builtin_amdgcn_mfma_f32_16x16x32_f16(af1, bf, accV[1][nt], 0, 0, 0);
      }
    }
    // V^T B-frags fully in-register (lane l15 = d ✓, k = m via lhi-repack)
    f16x8 vfrag[4];
#pragma unroll
    for (int nt = 0; nt < 4; ++nt) {
      float v16 = (lhi == 0) ? accV[1][nt][0] : 0.f;
      vfrag[nt] = repack_frag(accV[0][nt][0], accV[0][nt][1], accV[0][nt][2], accV[0][nt][3],
                              v16, l15, lhi);
    }

    // K A-frags for S^T (A rows = m; tile1 broadcast row 16)
    f16x8 kf0[2], kf1[2];
#pragma unroll
    for (int c = 0; c < 2; ++c) {
      kf0[c] = *(const f16x8*)(ksb + l15 * 144 + c * 64 + lhi * 16);
      kf1[c] = *(const f16x8*)(ksb + 16 * 144 + c * 64 + lhi * 16);
    }

    const f16* qb = q16h + ((size_t)(head * 16 + bs) * 77) * 64;
    float* ob = out + (size_t)b * 77 * 512 + head * 64;
    const float C2 = 0.18033688011112042f;  // log2(e)/8

#pragma unroll
    for (int nt = 0; nt < 5; ++nt) {
      f16x8 qf0 = *(const f16x8*)(qb + (nt * 16 + l15) * 64 + lhi * 8);
      f16x8 qf1 = *(const f16x8*)(qb + (nt * 16 + l15) * 64 + 32 + lhi * 8);
      f32x4 z = {0.f, 0.f, 0.f, 0.f};
      f32x4 s0 = z, s1 = z;
      s0 = __builtin_amdgcn_mfma_f32_16x16x32_f16(kf0[0], qf0, s0, 0, 0, 0);
      s0 = __builtin_amdgcn_mfma_f32_16x16x32_f16(kf0[1], qf1, s0, 0, 0, 0);
      s1 = __builtin_amdgcn_mfma_f32_16x16x32_f16(kf1[0], qf0, s1, 0, 0, 0);
      s1 = __builtin_amdgcn_mfma_f32_16x16x32_f16(kf1[1], qf1, s1, 0, 0, 0);
      // softmax over m (rows): 4 regs + m16 (s1 uniform) + lhi-reduction
      float mx = fmaxf(fmaxf(s0[0], s0[1]), fmaxf(s0[2], s0[3]));
      mx = fmaxf(mx, __shfl_xor(mx, 16));
      mx = fmaxf(mx, __shfl_xor(mx, 32));
      mx = fmaxf(mx, s1[0]);
      float e0[4];
#pragma unroll
      for (int r = 0; r < 4; ++r) e0[r] = exp2f((s0[r] - mx) * C2);
      float e1 = exp2f((s1[0] - mx) * C2);
      float sm = e0[0] + e0[1] + e0[2] + e0[3];
      sm += __shfl_xor(sm, 16);
      sm += __shfl_xor(sm, 32);
      sm += e1;
      float inv = fastrcp(sm);
#pragma unroll
      for (int r = 0; r < 4; ++r) e0[r] *= inv;
      e1 *= inv;
      f16x8 pfrag = repack_frag(e0[0], e0[1], e0[2], e0[3], (lhi == 0) ? e1 : 0.f, l15, lhi);
#pragma unroll
      for (int dt = 0; dt < 4; ++dt) {
        f32x4 o = {0.f, 0.f, 0.f, 0.f};
        o = __builtin_amdgcn_mfma_f32_16x16x32_f16(pfrag, vfrag[dt], o, 0, 0, 0);
#pragma unroll
        for (int r = 0; r < 4; ++r) {
          int n = nt * 16 + lhi * 4 + r;
          if (n < 77) ob[(size_t)n * 512 + dt * 16 + l15] = o[r];
        }
      }
    }
  }
}

extern "C" void kernel_launch(void* const* d_in, const int* in_sizes, int n_in,
                              void* d_out, int out_size, void* d_ws, size_t ws_size,
                              hipStream_t stream) {
  const float* xf = (const float*)d_in[0];
  const float* x = (const float*)d_in[1];
  const float* tn_g = (const float*)d_in[2];
  const float* tn_b = (const float*)d_in[3];
  const float* n_g = (const float*)d_in[4];
  const float* n_b = (const float*)d_in[5];
  const float* Wq = (const float*)d_in[6];
  const float* bq = (const float*)d_in[7];
  const float* Wk = (const float*)d_in[8];
  const float* bk = (const float*)d_in[9];
  const float* Wv = (const float*)d_in[10];
  const float* bv = (const float*)d_in[11];
  float* out = (float*)d_out;

  char* ws = (char*)d_ws;
  f16* q16h = (f16*)ws;                      // 8*16*77*64*2 = 1,261,568 B (+1024 pad)
  f16* Wcat = (f16*)(ws + 1262592);          // 1024*512*2   = 1,048,576 B
  f16* Wqh = (f16*)(ws + 2311168);           // 512*512*2    = 524,288 B
  float* bcat = (float*)(ws + 2835456);      // 1024*4       = 4,096 B

  prep_k<<<1536, 256, 0, stream>>>(Wq, Wk, bk, Wv, bv, Wcat, bcat, Wqh);
  qproj_k<<<dim3(16, 5), 256, 0, stream>>>(xf, tn_g, tn_b, Wqh, bq, q16h);
  fused_k<<<3888, 256, 0, stream>>>(x, n_g, n_b, Wcat, bcat, q16h, out);
}